// Round 1
// baseline (251.632 us; speedup 1.0000x reference)
//
#include <hip/hip_runtime.h>
#include <hip/hip_bf16.h>

#define D_IN  768
#define D_E   256
#define M_TOT 512      // B*S = 4*128
#define E_TOT 100000

typedef __attribute__((ext_vector_type(4))) float f32x4;
typedef __attribute__((ext_vector_type(8))) short bf16x8;

__device__ __forceinline__ short f2bf(float f) {
    union { float f; unsigned u; } x; x.f = f;
    unsigned r = x.u + 0x7fffu + ((x.u >> 16) & 1u);   // RNE
    return (short)(r >> 16);
}

// ---------------------------------------------------------------------------
// Kernel 1: q = tanh(x @ W^T + b)  -> bf16 q[512][256] + fp32 qinv[512]
// Tiled fp32 GEMM. Block = 4 output rows x all 256 entities; thread = entity.
// ---------------------------------------------------------------------------
#define TM 4
#define BK 32

__global__ __launch_bounds__(256) void proj_kernel(
    const float* __restrict__ x, const float* __restrict__ W,
    const float* __restrict__ b, unsigned short* __restrict__ qb,
    float* __restrict__ qinv)
{
    __shared__ float xs[TM][BK];
    __shared__ float ws[D_E * (BK + 1)];   // +1 pad: conflict-free ws[t*33+k]
    __shared__ float red[TM][4];

    const int t  = threadIdx.x;
    const int m0 = blockIdx.x * TM;
    float acc[TM] = {0.f, 0.f, 0.f, 0.f};

    for (int k0 = 0; k0 < D_IN; k0 += BK) {
        if (t < TM * BK) {
            int r = t / BK, c = t % BK;
            xs[r][c] = x[(size_t)(m0 + r) * D_IN + k0 + c];
        }
        #pragma unroll
        for (int i = 0; i < 8; ++i) {                 // 2048 float4 = 256x32
            int f   = i * 256 + t;
            int row = f >> 3;                          // 8 float4 per row
            int c4  = f & 7;
            const float4 wv = *reinterpret_cast<const float4*>(
                &W[(size_t)row * D_IN + k0 + c4 * 4]);
            float* dst = &ws[row * (BK + 1) + c4 * 4];
            dst[0] = wv.x; dst[1] = wv.y; dst[2] = wv.z; dst[3] = wv.w;
        }
        __syncthreads();
        #pragma unroll
        for (int k = 0; k < BK; ++k) {
            float wv = ws[t * (BK + 1) + k];
            #pragma unroll
            for (int m = 0; m < TM; ++m)
                acc[m] = fmaf(xs[m][k], wv, acc[m]);
        }
        __syncthreads();
    }

    const float bias = b[t];
    const int lane = t & 63, wid = t >> 6;
    #pragma unroll
    for (int m = 0; m < TM; ++m) {
        float q = tanhf(acc[m] + bias);
        acc[m] = q;
        float s = q * q;
        #pragma unroll
        for (int off = 1; off < 64; off <<= 1)
            s += __shfl_xor(s, off, 64);
        if (lane == 0) red[m][wid] = s;
    }
    __syncthreads();
    #pragma unroll
    for (int m = 0; m < TM; ++m) {
        qb[(size_t)(m0 + m) * D_E + t] = (unsigned short)f2bf(acc[m]);
        if (t == 0) {
            float s = red[m][0] + red[m][1] + red[m][2] + red[m][3];
            qinv[m0 + m] = 1.0f / fmaxf(sqrtf(s), 1e-8f);
        }
    }
}

// ---------------------------------------------------------------------------
// Kernel 2: out[m][n] = (q[m]·en[n]) * qinv[m] * einv[n]
// Block: 64 entity cols x ALL 512 m (entity read exactly once from HBM).
// 4 waves, each 128 m x 64 n. MFMA 16x16x32 bf16, swapped operands:
//   A-op = entity tile (rows = n), B-op = q (cols = m)
//   => D: col(lane&15) = m, rows(4*(lane>>4)+r) = n  -> float4 store along N.
// Entity sumsq accumulated in fp32 during fragment conversion; per-row scale
// applied in epilogue. Zero LDS.
// ---------------------------------------------------------------------------
#define BN 64
#define NF 4    // n fragments (16 each) per block
#define MF 8    // m fragments per wave (wave covers 128 m)

__global__ __launch_bounds__(256, 2) void sim_kernel(
    const float* __restrict__ en, const unsigned short* __restrict__ qb,
    const float* __restrict__ qinv, float* __restrict__ out)
{
    const int t    = threadIdx.x;
    const int lane = t & 63;
    const int wid  = t >> 6;
    const int n0   = blockIdx.x * BN;
    const int mwave = wid * 128;
    const int l15  = lane & 15;
    const int lk   = lane >> 4;            // 0..3 -> k-chunk / n-subrow group

    f32x4 acc[NF][MF];
    #pragma unroll
    for (int i = 0; i < NF; ++i)
        #pragma unroll
        for (int j = 0; j < MF; ++j)
            acc[i][j] = (f32x4){0.f, 0.f, 0.f, 0.f};

    float sq[NF] = {0.f, 0.f, 0.f, 0.f};

    const float* erow[NF];
    #pragma unroll
    for (int nf = 0; nf < NF; ++nf) {
        int n = n0 + nf * 16 + l15;
        if (n >= E_TOT) n = E_TOT - 1;      // clamp: loads safe, store masked
        erow[nf] = en + (size_t)n * D_E + lk * 8;
    }
    const unsigned short* qbase = qb + (size_t)(mwave + l15) * D_E + lk * 8;

    for (int kt = 0; kt < D_E; kt += 32) {
        bf16x8 ef[NF];
        #pragma unroll
        for (int nf = 0; nf < NF; ++nf) {
            const float4* p = reinterpret_cast<const float4*>(erow[nf] + kt);
            float4 a0 = p[0], a1 = p[1];
            sq[nf] += a0.x*a0.x + a0.y*a0.y + a0.z*a0.z + a0.w*a0.w
                    + a1.x*a1.x + a1.y*a1.y + a1.z*a1.z + a1.w*a1.w;
            bf16x8 v;
            v[0] = f2bf(a0.x); v[1] = f2bf(a0.y); v[2] = f2bf(a0.z); v[3] = f2bf(a0.w);
            v[4] = f2bf(a1.x); v[5] = f2bf(a1.y); v[6] = f2bf(a1.z); v[7] = f2bf(a1.w);
            ef[nf] = v;
        }
        #pragma unroll
        for (int mf = 0; mf < MF; ++mf) {
            const bf16x8 qf = *reinterpret_cast<const bf16x8*>(
                qbase + (size_t)mf * 16 * D_E + kt);
            #pragma unroll
            for (int nf = 0; nf < NF; ++nf)
                acc[nf][mf] = __builtin_amdgcn_mfma_f32_16x16x32_bf16(
                    ef[nf], qf, acc[nf][mf], 0, 0, 0);
        }
    }

    // entity scales: reduce sumsq across the 4 k-chunk lanes, then shuffle
    // to the D-layout lanes (reg r needs row n-offset lk*4+r).
    float escale[NF][4];
    #pragma unroll
    for (int nf = 0; nf < NF; ++nf) {
        float s = sq[nf];
        s += __shfl_xor(s, 16, 64);
        s += __shfl_xor(s, 32, 64);
        float sc = 1.0f / fmaxf(sqrtf(s), 1e-8f);
        #pragma unroll
        for (int r = 0; r < 4; ++r)
            escale[nf][r] = __shfl(sc, lk * 4 + r, 64);
    }

    #pragma unroll
    for (int mf = 0; mf < MF; ++mf) {
        const int m = mwave + mf * 16 + l15;
        const float qs = qinv[m];
        #pragma unroll
        for (int nf = 0; nf < NF; ++nf) {
            const int n = n0 + nf * 16 + lk * 4;
            if (n < E_TOT) {               // E%4==0 -> whole float4 valid
                float4 v;
                v.x = acc[nf][mf][0] * escale[nf][0] * qs;
                v.y = acc[nf][mf][1] * escale[nf][1] * qs;
                v.z = acc[nf][mf][2] * escale[nf][2] * qs;
                v.w = acc[nf][mf][3] * escale[nf][3] * qs;
                *reinterpret_cast<float4*>(&out[(size_t)m * E_TOT + n]) = v;
            }
        }
    }
}

// ---------------------------------------------------------------------------
extern "C" void kernel_launch(void* const* d_in, const int* in_sizes, int n_in,
                              void* d_out, int out_size, void* d_ws, size_t ws_size,
                              hipStream_t stream) {
    const float* x  = (const float*)d_in[0];   // [4,128,768]
    const float* W  = (const float*)d_in[1];   // [256,768]
    const float* b  = (const float*)d_in[2];   // [256]
    const float* en = (const float*)d_in[3];   // [100000,256]
    float* out = (float*)d_out;                // [512,100000]

    unsigned short* qb = (unsigned short*)d_ws;                    // 512*256 bf16
    float* qinv = (float*)((char*)d_ws + (size_t)M_TOT * D_E * 2); // 512 f32

    proj_kernel<<<M_TOT / TM, 256, 0, stream>>>(x, W, b, qb, qinv);

    const int nblocks = (E_TOT + BN - 1) / BN;   // 1563
    sim_kernel<<<nblocks, 256, 0, stream>>>(en, qb, qinv, out);
}

// Round 2
// 214.863 us; speedup vs baseline: 1.1711x; 1.1711x over previous
//
#include <hip/hip_runtime.h>
#include <hip/hip_bf16.h>

#define D_IN  768
#define D_E   256
#define M_TOT 512      // B*S = 4*128
#define E_TOT 100000

typedef __attribute__((ext_vector_type(4))) float f32x4;
typedef __attribute__((ext_vector_type(8))) short bf16x8;

__device__ __forceinline__ unsigned short bf16bits(float f) {
    union { __hip_bfloat16 h; unsigned short u; } c;
    c.h = __float2bfloat16(f);   // native cast -> compiler emits v_cvt_pk
    return c.u;
}

// ---------------------------------------------------------------------------
// Kernel 1: qb[m][e] = bf16( tanh(x@W^T + b) / ||row|| )   (pre-normalized)
// 256 blocks x 256 threads; block = 2 m-rows x 256 e. W tile (256x64) staged
// through registers -> LDS each round; next-round loads issued before the
// inner compute so HBM/L2 latency hides under the FMAs.
// ---------------------------------------------------------------------------
#define PTM 2
#define PBK 64
#define PROUNDS (D_IN / PBK)   // 12

__global__ __launch_bounds__(256) void proj_kernel(
    const float* __restrict__ x, const float* __restrict__ W,
    const float* __restrict__ b, unsigned short* __restrict__ qb)
{
    __shared__ float ws[D_E * (PBK + 1)];   // pad 65: reads (t+k)%32 -> 2-way (free)
    __shared__ float xs[PTM][PBK];
    __shared__ float red[PTM][4];

    const int t   = threadIdx.x;
    const int m0  = blockIdx.x * PTM;
    const int c4  = t & 15;      // float4-column within row
    const int rr  = t >> 4;      // row subgroup
    float4 wreg[16];
    float  xreg = 0.f;
    float  acc[PTM] = {0.f, 0.f};

    // tile loads: row = i*16+rr, 16 consecutive lanes cover one row's 64 floats
    #pragma unroll
    for (int i = 0; i < 16; ++i)
        wreg[i] = *reinterpret_cast<const float4*>(
            &W[(size_t)(i * 16 + rr) * D_IN + c4 * 4]);
    if (t < PTM * PBK)
        xreg = x[(size_t)(m0 + (t >> 6)) * D_IN + (t & 63)];

    for (int rd = 0; rd < PROUNDS; ++rd) {
        #pragma unroll
        for (int i = 0; i < 16; ++i) {
            float* dst = &ws[(i * 16 + rr) * (PBK + 1) + c4 * 4];
            dst[0] = wreg[i].x; dst[1] = wreg[i].y;
            dst[2] = wreg[i].z; dst[3] = wreg[i].w;
        }
        if (t < PTM * PBK) xs[t >> 6][t & 63] = xreg;
        __syncthreads();
        if (rd + 1 < PROUNDS) {        // issue next tile; lands during compute
            const int k0 = (rd + 1) * PBK;
            #pragma unroll
            for (int i = 0; i < 16; ++i)
                wreg[i] = *reinterpret_cast<const float4*>(
                    &W[(size_t)(i * 16 + rr) * D_IN + k0 + c4 * 4]);
            if (t < PTM * PBK)
                xreg = x[(size_t)(m0 + (t >> 6)) * D_IN + k0 + (t & 63)];
        }
        #pragma unroll
        for (int k = 0; k < PBK; ++k) {
            float wv = ws[t * (PBK + 1) + k];
            acc[0] = fmaf(xs[0][k], wv, acc[0]);
            acc[1] = fmaf(xs[1][k], wv, acc[1]);
        }
        __syncthreads();
    }

    const int lane = t & 63, wid = t >> 6;
    const float bias = b[t];
    float q[PTM];
    #pragma unroll
    for (int m = 0; m < PTM; ++m) {
        q[m] = tanhf(acc[m] + bias);
        float s = q[m] * q[m];
        #pragma unroll
        for (int off = 1; off < 64; off <<= 1) s += __shfl_xor(s, off, 64);
        if (lane == 0) red[m][wid] = s;
    }
    __syncthreads();
    #pragma unroll
    for (int m = 0; m < PTM; ++m) {
        float s = red[m][0] + red[m][1] + red[m][2] + red[m][3];
        float qinv = 1.0f / fmaxf(sqrtf(s), 1e-8f);
        qb[(size_t)(m0 + m) * D_E + t] = bf16bits(q[m] * qinv);
    }
}

// ---------------------------------------------------------------------------
// Kernel 2: out[m][n] = (qn[m] · e[n]) / ||e[n]||
// Block = 256 threads (4 waves), covers 256 m x 64 n; wave = 64 m x 64 n
// -> acc only 64 VGPR/wave, launch_bounds(256,3) => 3 waves/SIMD.
// Zero LDS, no barriers: waves free-run. Entity fp32 loaded, converted with
// native bf16 casts (cvt_pk), sumsq accumulated in fp32 for the epilogue
// scale. k-loop fully unrolled so the compiler hoists loads (prefetch).
// Nontemporal stores: out is write-once, keep L2/L3 for entities.
// Block swizzle: blocks w and w+8 within a 16-group share the entity tile
// (two m-halves) and land on the same XCD (bid%8 equal) for L2 reuse.
// ---------------------------------------------------------------------------
#define BN 64
#define NF 4
#define MF 4
#define NTILES 1568            // ceil(100000/64)=1563 padded to %8==0
#define SIM_GRID (NTILES * 2)  // 3136

__global__ __launch_bounds__(256, 3) void sim_kernel(
    const float* __restrict__ en, const unsigned short* __restrict__ qb,
    float* __restrict__ out)
{
    const int t    = threadIdx.x;
    const int lane = t & 63;
    const int wid  = t >> 6;
    const int l15  = lane & 15;
    const int lk   = lane >> 4;          // 0..3: k-chunk / n-subrow group

    const int bid   = blockIdx.x;
    const int g     = bid >> 4, w = bid & 15;
    const int tile  = g * 8 + (w & 7);   // 0..1567
    const int mhalf = w >> 3;
    const int n0    = tile * BN;
    const int m0    = mhalf * 256 + wid * 64;

    f32x4 acc[NF][MF];
    #pragma unroll
    for (int i = 0; i < NF; ++i)
        #pragma unroll
        for (int j = 0; j < MF; ++j)
            acc[i][j] = (f32x4){0.f, 0.f, 0.f, 0.f};

    float sq[NF] = {0.f, 0.f, 0.f, 0.f};

    const float* erow[NF];
    #pragma unroll
    for (int nf = 0; nf < NF; ++nf) {
        int n = n0 + nf * 16 + l15;
        if (n >= E_TOT) n = E_TOT - 1;   // clamp loads; stores masked below
        erow[nf] = en + (size_t)n * D_E + lk * 8;
    }
    const unsigned short* qbase = qb + (size_t)(m0 + l15) * D_E + lk * 8;

    #pragma unroll
    for (int ks = 0; ks < 8; ++ks) {
        const int kt = ks * 32;
        bf16x8 ef[NF];
        #pragma unroll
        for (int nf = 0; nf < NF; ++nf) {
            const float4* p = reinterpret_cast<const float4*>(erow[nf] + kt);
            float4 a0 = p[0], a1 = p[1];
            sq[nf] += a0.x*a0.x + a0.y*a0.y + a0.z*a0.z + a0.w*a0.w
                    + a1.x*a1.x + a1.y*a1.y + a1.z*a1.z + a1.w*a1.w;
            union { bf16x8 v; unsigned short s[8]; } u;
            u.s[0] = bf16bits(a0.x); u.s[1] = bf16bits(a0.y);
            u.s[2] = bf16bits(a0.z); u.s[3] = bf16bits(a0.w);
            u.s[4] = bf16bits(a1.x); u.s[5] = bf16bits(a1.y);
            u.s[6] = bf16bits(a1.z); u.s[7] = bf16bits(a1.w);
            ef[nf] = u.v;
        }
        #pragma unroll
        for (int mf = 0; mf < MF; ++mf) {
            const bf16x8 qf = *reinterpret_cast<const bf16x8*>(
                qbase + (size_t)mf * 16 * D_E + kt);
            #pragma unroll
            for (int nf = 0; nf < NF; ++nf)
                acc[nf][mf] = __builtin_amdgcn_mfma_f32_16x16x32_bf16(
                    ef[nf], qf, acc[nf][mf], 0, 0, 0);
        }
    }

    // entity inv-norms: reduce sumsq over the 4 k-chunk lanes, then place
    // scale for D-row lk*4+r into reg r (source lane lk*4+r < 16 holds it).
    float escale[NF][4];
    #pragma unroll
    for (int nf = 0; nf < NF; ++nf) {
        float s = sq[nf];
        s += __shfl_xor(s, 16, 64);
        s += __shfl_xor(s, 32, 64);
        float sc = 1.0f / fmaxf(sqrtf(s), 1e-8f);
        #pragma unroll
        for (int r = 0; r < 4; ++r)
            escale[nf][r] = __shfl(sc, lk * 4 + r, 64);
    }

    #pragma unroll
    for (int mf = 0; mf < MF; ++mf) {
        const int m = m0 + mf * 16 + l15;
        #pragma unroll
        for (int nf = 0; nf < NF; ++nf) {
            const int n = n0 + nf * 16 + lk * 4;
            if (n < E_TOT) {             // E%4==0 -> whole f32x4 valid
                f32x4 v;
                v[0] = acc[nf][mf][0] * escale[nf][0];
                v[1] = acc[nf][mf][1] * escale[nf][1];
                v[2] = acc[nf][mf][2] * escale[nf][2];
                v[3] = acc[nf][mf][3] * escale[nf][3];
                __builtin_nontemporal_store(
                    v, reinterpret_cast<f32x4*>(&out[(size_t)m * E_TOT + n]));
            }
        }
    }
}

// ---------------------------------------------------------------------------
extern "C" void kernel_launch(void* const* d_in, const int* in_sizes, int n_in,
                              void* d_out, int out_size, void* d_ws, size_t ws_size,
                              hipStream_t stream) {
    const float* x  = (const float*)d_in[0];   // [4,128,768]
    const float* W  = (const float*)d_in[1];   // [256,768]
    const float* b  = (const float*)d_in[2];   // [256]
    const float* en = (const float*)d_in[3];   // [100000,256]
    float* out = (float*)d_out;                // [512,100000]

    unsigned short* qb = (unsigned short*)d_ws;   // 512*256 bf16 (normalized)

    proj_kernel<<<M_TOT / PTM, 256, 0, stream>>>(x, W, b, qb);
    sim_kernel<<<SIM_GRID, 256, 0, stream>>>(en, qb, out);
}

// Round 3
// 199.835 us; speedup vs baseline: 1.2592x; 1.0752x over previous
//
#include <hip/hip_runtime.h>
#include <hip/hip_bf16.h>

#define D_IN  768
#define D_E   256
#define M_TOT 512      // B*S
#define E_TOT 100000

typedef __attribute__((ext_vector_type(4))) float f32x4;
typedef __attribute__((ext_vector_type(8))) short bf16x8;

__device__ __forceinline__ unsigned short bf16bits(float f) {
    union { __hip_bfloat16 h; unsigned short u; } c;
    c.h = __float2bfloat16(f);
    return c.u;
}

__device__ __forceinline__ void gload_lds16(const void* g, void* l) {
    __builtin_amdgcn_global_load_lds(
        (const __attribute__((address_space(1))) void*)g,
        (__attribute__((address_space(3))) void*)l, 16, 0, 0);
}

// ---------------------------------------------------------------------------
// Kernel 0: eb[n][k] = bf16( en[n][k] / ||en[n]|| )   (pre-normalized entities)
// One wave per row per iter: lane loads f32x4 (16B, 1KB/instr contiguous),
// shfl-reduce sumsq, scale, store 8B/lane (512B/instr contiguous).
// 3125 blocks x 4 waves x 8 rows = 100000 exact.
// ---------------------------------------------------------------------------
__global__ __launch_bounds__(256) void prep_kernel(
    const float* __restrict__ en, unsigned short* __restrict__ eb)
{
    const int lane = threadIdx.x & 63;
    const int gw   = blockIdx.x * 4 + (threadIdx.x >> 6);
    #pragma unroll 2
    for (int i = 0; i < 8; ++i) {
        const int row = gw * 8 + i;
        const float4 v = *reinterpret_cast<const float4*>(
            en + (size_t)row * D_E + lane * 4);
        float s = v.x*v.x + v.y*v.y + v.z*v.z + v.w*v.w;
        #pragma unroll
        for (int off = 1; off < 64; off <<= 1) s += __shfl_xor(s, off, 64);
        const float sc = 1.0f / fmaxf(sqrtf(s), 1e-8f);
        union { unsigned short u[4]; uint2 d; } o;
        o.u[0] = bf16bits(v.x * sc); o.u[1] = bf16bits(v.y * sc);
        o.u[2] = bf16bits(v.z * sc); o.u[3] = bf16bits(v.w * sc);
        *reinterpret_cast<uint2*>(eb + (size_t)row * D_E + lane * 4) = o.d;
    }
}

// ---------------------------------------------------------------------------
// Kernel 1: qb[m][e] = bf16( tanh(x@W^T + b) / ||row|| )   (pre-normalized)
// ---------------------------------------------------------------------------
#define PTM 2
#define PBK 64
#define PROUNDS (D_IN / PBK)   // 12

__global__ __launch_bounds__(256) void proj_kernel(
    const float* __restrict__ x, const float* __restrict__ W,
    const float* __restrict__ b, unsigned short* __restrict__ qb)
{
    __shared__ float ws[D_E * (PBK + 1)];
    __shared__ float xs[PTM][PBK];
    __shared__ float red[PTM][4];

    const int t  = threadIdx.x;
    const int m0 = blockIdx.x * PTM;
    const int c4 = t & 15;
    const int rr = t >> 4;
    float4 wreg[16];
    float  xreg = 0.f;
    float  acc[PTM] = {0.f, 0.f};

    #pragma unroll
    for (int i = 0; i < 16; ++i)
        wreg[i] = *reinterpret_cast<const float4*>(
            &W[(size_t)(i * 16 + rr) * D_IN + c4 * 4]);
    if (t < PTM * PBK)
        xreg = x[(size_t)(m0 + (t >> 6)) * D_IN + (t & 63)];

    for (int rd = 0; rd < PROUNDS; ++rd) {
        #pragma unroll
        for (int i = 0; i < 16; ++i) {
            float* dst = &ws[(i * 16 + rr) * (PBK + 1) + c4 * 4];
            dst[0] = wreg[i].x; dst[1] = wreg[i].y;
            dst[2] = wreg[i].z; dst[3] = wreg[i].w;
        }
        if (t < PTM * PBK) xs[t >> 6][t & 63] = xreg;
        __syncthreads();
        if (rd + 1 < PROUNDS) {
            const int k0 = (rd + 1) * PBK;
            #pragma unroll
            for (int i = 0; i < 16; ++i)
                wreg[i] = *reinterpret_cast<const float4*>(
                    &W[(size_t)(i * 16 + rr) * D_IN + k0 + c4 * 4]);
            if (t < PTM * PBK)
                xreg = x[(size_t)(m0 + (t >> 6)) * D_IN + k0 + (t & 63)];
        }
        #pragma unroll
        for (int k = 0; k < PBK; ++k) {
            float wv = ws[t * (PBK + 1) + k];
            acc[0] = fmaf(xs[0][k], wv, acc[0]);
            acc[1] = fmaf(xs[1][k], wv, acc[1]);
        }
        __syncthreads();
    }

    const int lane = t & 63, wid = t >> 6;
    const float bias = b[t];
    float q[PTM];
    #pragma unroll
    for (int m = 0; m < PTM; ++m) {
        q[m] = tanhf(acc[m] + bias);
        float s = q[m] * q[m];
        #pragma unroll
        for (int off = 1; off < 64; off <<= 1) s += __shfl_xor(s, off, 64);
        if (lane == 0) red[m][wid] = s;
    }
    __syncthreads();
    #pragma unroll
    for (int m = 0; m < PTM; ++m) {
        float s = red[m][0] + red[m][1] + red[m][2] + red[m][3];
        float qinv = 1.0f / fmaxf(sqrtf(s), 1e-8f);
        qb[(size_t)(m0 + m) * D_E + t] = bf16bits(q[m] * qinv);
    }
}

// ---------------------------------------------------------------------------
// Kernel 2: out[m][n] = qn[m] · en_hat[n]   (both operands pre-normalized bf16)
// Block = 512 thr (8 waves, 4m x 2n of 64x32 wave tiles) = 256m x 64n tile.
// Entity tile (64 x 256 bf16 = 32KB) staged once via global_load_lds with
// source pre-swizzle (c16 ^= row&7) so ds_read_b128 A-frags are bank-optimal.
// K=256 fits in one stage: no k-loop staging, 1 barrier. q read direct from
// L2 (256KB resident). Swapped MFMA operands (validated r1): D col = m.
// ---------------------------------------------------------------------------
#define BM 256
#define BN 64
#define NT 1563          // ceil(100000/64)
#define SIM_GRID (NT * 2)

__global__ __launch_bounds__(512, 4) void sim_kernel(
    const unsigned short* __restrict__ eb, const unsigned short* __restrict__ qb,
    float* __restrict__ out)
{
    __shared__ unsigned short es[BN * D_E];   // 32 KB, source-swizzled

    const int t    = threadIdx.x;
    const int lane = t & 63;
    const int wid  = t >> 6;
    const int l15  = lane & 15;
    const int lk   = lane >> 4;

    // bijective XCD swizzle (m204): each XCD gets a contiguous work chunk ->
    // the 2 m-tiles sharing an entity tile co-run on one XCD's L2.
    int bid = blockIdx.x;
    {
        const int q = SIM_GRID >> 3, r = SIM_GRID & 7;
        const int xcd = bid & 7, rk = bid >> 3;
        bid = (xcd < r ? xcd * (q + 1) : r * (q + 1) + (xcd - r) * q) + rk;
    }
    const int n0 = (bid >> 1) * BN;
    const int m0 = (bid & 1) * BM;
    const int wn = (wid & 1) * 32;
    const int wm = (wid >> 1) * 64;

    // ---- stage entity tile: 4 rounds x 512 thr x 16B. LDS dest linear;
    // source column pre-swizzled so swizzled ds_reads return true data.
    #pragma unroll
    for (int j = 0; j < 4; ++j) {
        const int tb  = j * 512 + t;      // 16B-unit index in tile
        const int row = tb >> 5;          // 0..63
        const int c16 = tb & 31;
        int rg = n0 + row; if (rg >= E_TOT) rg = E_TOT - 1;
        const unsigned short* src =
            eb + (size_t)rg * D_E + ((c16 ^ (row & 7)) << 3);
        gload_lds16(src, (void*)&es[(size_t)tb << 3]);
    }
    __syncthreads();

    f32x4 acc[2][4];
    #pragma unroll
    for (int i = 0; i < 2; ++i)
        #pragma unroll
        for (int j = 0; j < 4; ++j)
            acc[i][j] = (f32x4){0.f, 0.f, 0.f, 0.f};

    const unsigned short* qrow[4];
    #pragma unroll
    for (int mf = 0; mf < 4; ++mf)
        qrow[mf] = qb + (size_t)(m0 + wm + mf * 16 + l15) * D_E + lk * 8;

    const char* esb = reinterpret_cast<const char*>(es);

    #pragma unroll 2
    for (int ks = 0; ks < 8; ++ks) {
        bf16x8 ef[2];
        #pragma unroll
        for (int nf = 0; nf < 2; ++nf) {
            const int row = wn + nf * 16 + l15;
            const int cb  = (ks * 64 + lk * 16) ^ ((row & 7) << 4);
            ef[nf] = *reinterpret_cast<const bf16x8*>(esb + row * 512 + cb);
        }
        #pragma unroll
        for (int mf = 0; mf < 4; ++mf) {
            const bf16x8 qf =
                *reinterpret_cast<const bf16x8*>(qrow[mf] + ks * 32);
            acc[0][mf] = __builtin_amdgcn_mfma_f32_16x16x32_bf16(
                ef[0], qf, acc[0][mf], 0, 0, 0);
            acc[1][mf] = __builtin_amdgcn_mfma_f32_16x16x32_bf16(
                ef[1], qf, acc[1][mf], 0, 0, 0);
        }
    }

    // epilogue: no scales (both operands pre-normalized). Plain stores:
    // L2 merges the 64B row-segments (round-1 WRITE_SIZE was exactly ideal).
    #pragma unroll
    for (int mf = 0; mf < 4; ++mf) {
        const int m = m0 + wm + mf * 16 + l15;
        #pragma unroll
        for (int nf = 0; nf < 2; ++nf) {
            const int n = n0 + wn + nf * 16 + lk * 4;
            if (n < E_TOT)
                *reinterpret_cast<f32x4*>(&out[(size_t)m * E_TOT + n]) =
                    acc[nf][mf];
        }
    }
}

// ---------------------------------------------------------------------------
extern "C" void kernel_launch(void* const* d_in, const int* in_sizes, int n_in,
                              void* d_out, int out_size, void* d_ws, size_t ws_size,
                              hipStream_t stream) {
    const float* x  = (const float*)d_in[0];   // [4,128,768]
    const float* W  = (const float*)d_in[1];   // [256,768]
    const float* b  = (const float*)d_in[2];   // [256]
    const float* en = (const float*)d_in[3];   // [100000,256]
    float* out = (float*)d_out;                // [512,100000]

    unsigned short* qb = (unsigned short*)d_ws;                 // 256 KB
    unsigned short* eb = (unsigned short*)((char*)d_ws + (size_t)M_TOT * D_E * 2);
                                                                // 51.2 MB

    prep_kernel<<<E_TOT / 32, 256, 0, stream>>>(en, eb);        // 3125 blocks
    proj_kernel<<<M_TOT / PTM, 256, 0, stream>>>(x, W, b, qb);  // 256 blocks
    sim_kernel<<<SIM_GRID, 512, 0, stream>>>(eb, qb, out);      // 3126 blocks
}

// Round 4
// 178.010 us; speedup vs baseline: 1.4136x; 1.1226x over previous
//
#include <hip/hip_runtime.h>
#include <hip/hip_bf16.h>

#define D_IN  768
#define D_E   256
#define M_TOT 512      // B*S
#define E_TOT 100000

typedef __attribute__((ext_vector_type(4))) float f32x4;
typedef __attribute__((ext_vector_type(8))) short bf16x8;

__device__ __forceinline__ unsigned short bf16bits(float f) {
    union { __hip_bfloat16 h; unsigned short u; } c;
    c.h = __float2bfloat16(f);
    return c.u;
}

__device__ __forceinline__ void gload_lds16(const void* g, void* l) {
    __builtin_amdgcn_global_load_lds(
        (const __attribute__((address_space(1))) void*)g,
        (__attribute__((address_space(3))) void*)l, 16, 0, 0);
}

// ---------------------------------------------------------------------------
// Kernel 0: eb[n][k] = bf16( en[n][k] / ||en[n]|| )
// 3125 blocks x 4 waves x 8 rows. ~BW floor (153 MB).
// ---------------------------------------------------------------------------
__global__ __launch_bounds__(256) void prep_kernel(
    const float* __restrict__ en, unsigned short* __restrict__ eb)
{
    const int lane = threadIdx.x & 63;
    const int gw   = blockIdx.x * 4 + (threadIdx.x >> 6);
    #pragma unroll 2
    for (int i = 0; i < 8; ++i) {
        const int row = gw * 8 + i;
        const float4 v = *reinterpret_cast<const float4*>(
            en + (size_t)row * D_E + lane * 4);
        float s = v.x*v.x + v.y*v.y + v.z*v.z + v.w*v.w;
        #pragma unroll
        for (int off = 1; off < 64; off <<= 1) s += __shfl_xor(s, off, 64);
        const float sc = 1.0f / fmaxf(sqrtf(s), 1e-8f);
        union { unsigned short u[4]; uint2 d; } o;
        o.u[0] = bf16bits(v.x * sc); o.u[1] = bf16bits(v.y * sc);
        o.u[2] = bf16bits(v.z * sc); o.u[3] = bf16bits(v.w * sc);
        *reinterpret_cast<uint2*>(eb + (size_t)row * D_E + lane * 4) = o.d;
    }
}

// ---------------------------------------------------------------------------
// Kernel 1: qb[m][e] = bf16( tanh(x@W^T + b) / ||row|| )
// PTM=8 -> 64 blocks: W L3 re-read traffic 196 MB -> 49 MB.
// ---------------------------------------------------------------------------
#define PTM 8
#define PBK 64
#define PROUNDS (D_IN / PBK)   // 12

__global__ __launch_bounds__(256) void proj_kernel(
    const float* __restrict__ x, const float* __restrict__ W,
    const float* __restrict__ b, unsigned short* __restrict__ qb)
{
    __shared__ float ws[D_E * (PBK + 1)];   // 65 KB (64 blocks only -> fine)
    __shared__ float xs[PTM][PBK];
    __shared__ float red[PTM][4];

    const int t  = threadIdx.x;
    const int m0 = blockIdx.x * PTM;
    const int c4 = t & 15;
    const int rr = t >> 4;
    float4 wreg[16];
    float  xreg[2];
    float  acc[PTM];
    #pragma unroll
    for (int m = 0; m < PTM; ++m) acc[m] = 0.f;

    #pragma unroll
    for (int i = 0; i < 16; ++i)
        wreg[i] = *reinterpret_cast<const float4*>(
            &W[(size_t)(i * 16 + rr) * D_IN + c4 * 4]);
    #pragma unroll
    for (int i = 0; i < 2; ++i) {
        int f = i * 256 + t;
        xreg[i] = x[(size_t)(m0 + (f >> 6)) * D_IN + (f & 63)];
    }

    for (int rd = 0; rd < PROUNDS; ++rd) {
        #pragma unroll
        for (int i = 0; i < 16; ++i) {
            float* dst = &ws[(i * 16 + rr) * (PBK + 1) + c4 * 4];
            dst[0] = wreg[i].x; dst[1] = wreg[i].y;
            dst[2] = wreg[i].z; dst[3] = wreg[i].w;
        }
        #pragma unroll
        for (int i = 0; i < 2; ++i) {
            int f = i * 256 + t;
            xs[f >> 6][f & 63] = xreg[i];
        }
        __syncthreads();
        if (rd + 1 < PROUNDS) {
            const int k0 = (rd + 1) * PBK;
            #pragma unroll
            for (int i = 0; i < 16; ++i)
                wreg[i] = *reinterpret_cast<const float4*>(
                    &W[(size_t)(i * 16 + rr) * D_IN + k0 + c4 * 4]);
            #pragma unroll
            for (int i = 0; i < 2; ++i) {
                int f = i * 256 + t;
                xreg[i] = x[(size_t)(m0 + (f >> 6)) * D_IN + k0 + (f & 63)];
            }
        }
        #pragma unroll
        for (int k = 0; k < PBK; ++k) {
            float wv = ws[t * (PBK + 1) + k];
            #pragma unroll
            for (int m = 0; m < PTM; ++m)
                acc[m] = fmaf(xs[m][k], wv, acc[m]);
        }
        __syncthreads();
    }

    const int lane = t & 63, wid = t >> 6;
    const float bias = b[t];
    float q[PTM];
    #pragma unroll
    for (int m = 0; m < PTM; ++m) {
        q[m] = tanhf(acc[m] + bias);
        float s = q[m] * q[m];
        #pragma unroll
        for (int off = 1; off < 64; off <<= 1) s += __shfl_xor(s, off, 64);
        if (lane == 0) red[m][wid] = s;
    }
    __syncthreads();
    #pragma unroll
    for (int m = 0; m < PTM; ++m) {
        float s = red[m][0] + red[m][1] + red[m][2] + red[m][3];
        float qinv = 1.0f / fmaxf(sqrtf(s), 1e-8f);
        qb[(size_t)(m0 + m) * D_E + t] = bf16bits(q[m] * qinv);
    }
}

// ---------------------------------------------------------------------------
// Kernel 2: out[m][n] = qn[m] . en_hat[n]  (both pre-normalized bf16)
// Block = 256 thr (4 waves), tile 128m x 64n; wave = 32m x 64n.
// q panel persistent in registers (16 bf16x8 / lane, loaded ONCE) -> hot loop
// is pure ds_read_b128 + MFMA. Entity tile (32 KB) staged via global_load_lds
// with the validated source pre-swizzle. Each block processes 2 n-tiles.
// ---------------------------------------------------------------------------
#define BN 64
#define NT 1563                 // ceil(100000/64)
#define TILES_PER 2
#define NGRP ((NT + TILES_PER - 1) / TILES_PER)   // 782
#define SIM_GRID (NGRP * 4)     // 3128

__global__ __launch_bounds__(256, 4) void sim_kernel(
    const unsigned short* __restrict__ eb, const unsigned short* __restrict__ qb,
    float* __restrict__ out)
{
    __shared__ unsigned short es[BN * D_E];   // 32 KB

    const int t    = threadIdx.x;
    const int lane = t & 63;
    const int wid  = t >> 6;          // 0..3
    const int l15  = lane & 15;
    const int lk   = lane >> 4;       // 0..3

    // bijective chunked XCD swizzle: consecutive bids (the 4 m-groups of one
    // n-group) land on the SAME XCD -> entity tile L2 reuse.
    int bid = blockIdx.x;
    {
        const int qq = SIM_GRID >> 3, r = SIM_GRID & 7;
        const int xcd = bid & 7, rk = bid >> 3;
        bid = (xcd < r ? xcd * (qq + 1) : r * (qq + 1) + (xcd - r) * qq) + rk;
    }
    const int mg  = bid & 3;
    const int grp = bid >> 2;         // 0..781
    const int m0  = mg * 128;

    // ---- q panel: persistent registers, loaded once (64 VGPR) ----
    bf16x8 qf[2][8];
    #pragma unroll
    for (int mf = 0; mf < 2; ++mf) {
        const unsigned short* base =
            qb + (size_t)(m0 + wid * 32 + mf * 16 + l15) * D_E + lk * 8;
        #pragma unroll
        for (int ks = 0; ks < 8; ++ks)
            qf[mf][ks] = *reinterpret_cast<const bf16x8*>(base + ks * 32);
    }

    const char* esb = reinterpret_cast<const char*>(es);

    for (int i = 0; i < TILES_PER; ++i) {
        const int tile = grp * TILES_PER + i;
        if (tile >= NT) break;                 // block-uniform
        const int n0 = tile * BN;

        if (i) __syncthreads();                // es reads of prev tile done
        // stage entity tile: 2048 x 16B chunks / 256 thr = 8 per thread.
        // LDS dest linear (wave-uniform base + lane*16); source pre-swizzled.
        #pragma unroll
        for (int j = 0; j < 8; ++j) {
            const int tb  = j * 256 + t;       // 16B-chunk index
            const int row = tb >> 5;           // 0..63
            const int c16 = tb & 31;
            int rg = n0 + row; if (rg >= E_TOT) rg = E_TOT - 1;
            const unsigned short* src =
                eb + (size_t)rg * D_E + ((c16 ^ (row & 7)) << 3);
            gload_lds16(src, (void*)&es[(size_t)tb << 3]);
        }
        __syncthreads();

        f32x4 acc[2][4];
        #pragma unroll
        for (int mf = 0; mf < 2; ++mf)
            #pragma unroll
            for (int nf = 0; nf < 4; ++nf)
                acc[mf][nf] = (f32x4){0.f, 0.f, 0.f, 0.f};

        #pragma unroll
        for (int ks = 0; ks < 8; ++ks) {
            bf16x8 ef[4];
            #pragma unroll
            for (int nf = 0; nf < 4; ++nf) {
                const int row = nf * 16 + l15;
                const int cb  = (ks * 64 + lk * 16) ^ ((row & 7) << 4);
                ef[nf] = *reinterpret_cast<const bf16x8*>(esb + row * 512 + cb);
            }
            #pragma unroll
            for (int mf = 0; mf < 2; ++mf)
                #pragma unroll
                for (int nf = 0; nf < 4; ++nf)
                    acc[mf][nf] = __builtin_amdgcn_mfma_f32_16x16x32_bf16(
                        ef[nf], qf[mf][ks], acc[mf][nf], 0, 0, 0);
        }

        #pragma unroll
        for (int mf = 0; mf < 2; ++mf) {
            const int m = m0 + wid * 32 + mf * 16 + l15;
            #pragma unroll
            for (int nf = 0; nf < 4; ++nf) {
                const int n = n0 + nf * 16 + lk * 4;
                if (n < E_TOT)
                    *reinterpret_cast<f32x4*>(&out[(size_t)m * E_TOT + n]) =
                        acc[mf][nf];
            }
        }
    }
}

// ---------------------------------------------------------------------------
extern "C" void kernel_launch(void* const* d_in, const int* in_sizes, int n_in,
                              void* d_out, int out_size, void* d_ws, size_t ws_size,
                              hipStream_t stream) {
    const float* x  = (const float*)d_in[0];   // [4,128,768]
    const float* W  = (const float*)d_in[1];   // [256,768]
    const float* b  = (const float*)d_in[2];   // [256]
    const float* en = (const float*)d_in[3];   // [100000,256]
    float* out = (float*)d_out;                // [512,100000]

    unsigned short* qb = (unsigned short*)d_ws;                 // 256 KB
    unsigned short* eb = (unsigned short*)((char*)d_ws + (size_t)M_TOT * D_E * 2);

    prep_kernel<<<E_TOT / 32, 256, 0, stream>>>(en, eb);        // 3125 blocks
    proj_kernel<<<M_TOT / PTM, 256, 0, stream>>>(x, W, b, qb);  // 64 blocks
    sim_kernel<<<SIM_GRID, 256, 0, stream>>>(eb, qb, out);      // 3128 blocks
}